// Round 8
// baseline (1077.727 us; speedup 1.0000x reference)
//
#include <hip/hip_runtime.h>
#include <cstdint>
#include <cstddef>

#define NN      20000
#define RR      4
#define EE      40000
#define CIN     256
#define CEDGE   128
#define HIDW    512
#define OUTW    256
#define NH      8
#define MEDGE   (RR*EE)
#define SCALEF  0.125f

typedef unsigned short u16;
typedef short s8v  __attribute__((ext_vector_type(8)));
typedef float f32x4 __attribute__((ext_vector_type(4)));

// ---- ws layout (BYTE offsets) ----
#define B_KQV   10240000ull             // 20000*1536*2 = 61,440,000
#define B_KREL  71680000ull             // 20000*2048*2 = 81,920,000 (wsumH overlays after alpha)
#define B_AGG   153600000ull            // 20000*512*2
#define B_H0    174080000ull            // 20000*512*2
#define B_H1    194560000ull            // 20000*512*2
#define B_ALPHA 215040000ull             // 160000*8*4 = 5,120,000 (f32)
#define B_LSE   220160000ull            // 20000*8*4 (f32); fillcnt overlay during CSR build
#define B_ROWP  220800000ull            // 20001*4 -> pad
#define B_EREC  220880128ull            // 160000*4
#define B_WTS   221520128ull            // bf16 weights, ~5.2 MB
#define WS_NEED 227000000ull

#define SZH ((size_t)NN * 256)          // elements per head-matrix (wsumH)

__device__ __forceinline__ u16 f2b(float f) {
    unsigned u = __float_as_uint(f);
    unsigned r = (u + 0x7FFFu + ((u >> 16) & 1u)) >> 16;
    return (u16)r;
}
__device__ __forceinline__ float b2f(u16 h) { return __uint_as_float(((unsigned)h) << 16); }
__device__ __forceinline__ float gelu_exact(float x) {
    return 0.5f * x * (1.0f + erff(x * 0.70710678118654752f));
}

// async global->LDS, 16 bytes per lane; LDS dest must be wave-uniform base
__device__ __forceinline__ void gl_lds16(const u16* g, u16* l) {
    __builtin_amdgcn_global_load_lds(
        (const __attribute__((address_space(1))) void*)g,
        (__attribute__((address_space(3))) void*)l, 16, 0, 0);
}

// =============== generic bf16 MFMA GEMM (R6 single-buffered version) ===============
// A: M x K row-major (lda) — bf16, or f32 converted during staging when AF32.
// BT: N x K bf16 row-major (ldb). C: M x N (ldc). batched over blockIdx.z via strides.
// K%64==0, N%BN==0, M guarded (rows clamped on load).
// LDS layout: As[row][chunk] (chunk = 8 elems / 16B) holds global chunk (chunk ^ (row&7)).
// ACT: 0 none, 1 relu, 2 gelu. SKIP: out = g*out+(1-g)*skipx (bf16).
template<int BN, int ACT, bool OUTBF16, bool BIAS, bool SKIP, bool AF32 = false>
__global__ __launch_bounds__(256) void gemm_bf16(
    const void* __restrict__ Av, int lda, size_t astride,
    const u16* __restrict__ BT, int ldb, size_t bstride,
    const float* __restrict__ bias,
    void* __restrict__ Cv, int ldc, size_t cstride,
    int M, int K,
    const u16* __restrict__ skipx, const float* __restrict__ gatep)
{
    constexpr int FN = BN / 32;         // frags per wave along N (wave covers BN/2)
    constexpr int BI = BN / 32;         // B stage instructions per wave
    __shared__ __align__(16) u16 As[128 * 64];
    __shared__ __align__(16) u16 Bs[BN * 64];

    const int t = threadIdx.x, lane = t & 63, wid = t >> 6;
    const int m0 = blockIdx.y * 128, n0 = blockIdx.x * BN;
    const int z  = blockIdx.z;
    const u16*   Bz = BT + (size_t)z * bstride;
    const float* Af = (const float*)Av + (AF32 ? (size_t)z * astride : 0);
    const u16*   Au = (const u16*)Av   + (AF32 ? 0 : (size_t)z * astride);
    const int wm = wid >> 1, wn = wid & 1;

    // per-lane staging constants: lane covers row-in-group (lane>>3), swizzled k-chunk
    const int srow   = lane >> 3;
    const int schunk = (lane & 7) ^ srow;

    f32x4 acc[4][FN];
    #pragma unroll
    for (int i = 0; i < 4; ++i)
        #pragma unroll
        for (int j = 0; j < FN; ++j)
            acc[i][j] = (f32x4){0.f, 0.f, 0.f, 0.f};

    for (int k0 = 0; k0 < K; k0 += 64) {
        if (AF32) {
            // reg staging with f32->bf16 convert; write to swizzled chunk
            #pragma unroll
            for (int i = 0; i < 4; ++i) {
                int c = i * 256 + t;
                int row = c >> 3, cc = c & 7;
                int gr = m0 + row; gr = gr < M ? gr : M - 1;
                const float* Ap = Af + (size_t)gr * lda + k0 + cc * 8;
                float4 p = *(const float4*)Ap;
                float4 q = *(const float4*)(Ap + 4);
                s8v v;
                v[0] = (short)f2b(p.x); v[1] = (short)f2b(p.y);
                v[2] = (short)f2b(p.z); v[3] = (short)f2b(p.w);
                v[4] = (short)f2b(q.x); v[5] = (short)f2b(q.y);
                v[6] = (short)f2b(q.z); v[7] = (short)f2b(q.w);
                *(s8v*)&As[row * 64 + ((cc ^ (row & 7)) << 3)] = v;
            }
        } else {
            // async staging: 16 wave-instructions cover 128 rows x 64 k
            #pragma unroll
            for (int i = 0; i < 4; ++i) {
                int t4 = wid * 4 + i;
                int row = t4 * 8 + srow;
                int gr = m0 + row; gr = gr < M ? gr : M - 1;
                gl_lds16(Au + (size_t)gr * lda + k0 + schunk * 8, &As[t4 * 512]);
            }
        }
        #pragma unroll
        for (int i = 0; i < BI; ++i) {
            int tb = wid * BI + i;
            int col = n0 + tb * 8 + srow;
            gl_lds16(Bz + (size_t)col * ldb + k0 + schunk * 8, &Bs[tb * 512]);
        }
        __syncthreads();   // drains vmcnt (incl. global_load_lds) + lgkmcnt
        #pragma unroll
        for (int ks = 0; ks < 2; ++ks) {
            s8v af[4], bf[FN];
            #pragma unroll
            for (int i = 0; i < 4; ++i) {
                int arow = wm * 64 + i * 16 + (lane & 15);
                int ac   = (ks * 4 + (lane >> 4)) ^ (lane & 7);
                af[i] = *(const s8v*)&As[arow * 64 + ac * 8];
            }
            #pragma unroll
            for (int j = 0; j < FN; ++j) {
                int brow = wn * (BN / 2) + j * 16 + (lane & 15);
                int bc   = (ks * 4 + (lane >> 4)) ^ (lane & 7);
                bf[j] = *(const s8v*)&Bs[brow * 64 + bc * 8];
            }
            #pragma unroll
            for (int i = 0; i < 4; ++i)
                #pragma unroll
                for (int j = 0; j < FN; ++j)
                    acc[i][j] = __builtin_amdgcn_mfma_f32_16x16x32_bf16(af[i], bf[j], acc[i][j], 0, 0, 0);
        }
        __syncthreads();
    }

    float gate = 1.f, ogate = 0.f;
    if (SKIP) { float s = *gatep; gate = 1.f / (1.f + expf(-s)); ogate = 1.f - gate; }
    u16*   Cb = (u16*)Cv   + (size_t)z * cstride;
    float* Cf = (float*)Cv + (size_t)z * cstride;
    #pragma unroll
    for (int i = 0; i < 4; ++i) {
        int rbase = m0 + wm * 64 + i * 16 + (lane >> 4) * 4;
        #pragma unroll
        for (int j = 0; j < FN; ++j) {
            int col = n0 + wn * (BN / 2) + j * 16 + (lane & 15);
            float bv = BIAS ? bias[col] : 0.f;
            #pragma unroll
            for (int q = 0; q < 4; ++q) {
                int r = rbase + q;
                if (r >= M) continue;
                float v = acc[i][j][q] + bv;
                if (ACT == 1) v = fmaxf(v, 0.f);
                if (ACT == 2) v = gelu_exact(v);
                if (SKIP) v = gate * v + ogate * b2f(skipx[(size_t)r * ldc + col]);
                if (OUTBF16) Cb[(size_t)r * ldc + col] = f2b(v);
                else         Cf[(size_t)r * ldc + col] = v;
            }
        }
    }
}

// =============== fused edge MLP v3 — wave-private, ZERO barriers ===============
// out = relu(ea @ We1 + b1) @ We2 + b2.
// 4 waves x 16 edge-rows per block; each wave owns private Ae[16][128] and Ic[16][128]
// LDS slices (8 KB/wave). No __syncthreads anywhere: all LDS traffic is in-wave
// (DS pipe is in-order per wave; compiler inserts lgkmcnt for RAW).
// Stage 1 (per 128-col interm chunk): I = relu(A @ We1_c + b1_c) -> private Ic.
// Stage 2: out[16][256] += Ic @ We2_c (16 n-frags, B streamed from L2-resident We2T).
__global__ __launch_bounds__(256) void edge_mlp(
    const float* __restrict__ ea, const u16* __restrict__ We1T,
    const float* __restrict__ b1, const u16* __restrict__ We2T,
    const float* __restrict__ b2, float* __restrict__ out)
{
    __shared__ __align__(16) u16 AeAll[4][16 * 128];
    __shared__ __align__(16) u16 IcAll[4][16 * 128];

    const int t = threadIdx.x, lane = t & 63, w = t >> 6;
    u16* Ae = AeAll[w];
    u16* Ic = IcAll[w];
    const int r0 = blockIdx.x * 64 + w * 16;     // this wave's first edge row
    const int l15 = lane & 15, l4 = lane >> 4;

    // ---- load A tile: 16 rows x 128 f32, coalesced float4; cvt -> bf16x4 (8B) LDS writes
    #pragma unroll
    for (int i = 0; i < 8; ++i) {
        int f   = i * 64 + lane;        // float4 index 0..511
        int row = f >> 5;               // 0..15
        int c4  = f & 31;               // float4 within row
        float4 p = *(const float4*)(ea + (size_t)(r0 + row) * 128 + c4 * 4);
        unsigned lo = (unsigned)f2b(p.x) | ((unsigned)f2b(p.y) << 16);
        unsigned hi = (unsigned)f2b(p.z) | ((unsigned)f2b(p.w) << 16);
        int chunk = c4 >> 1;            // 16B chunk 0..15
        int sub   = (c4 & 1) * 8;       // byte offset within chunk
        *(uint2*)((char*)Ae + row * 256 + ((chunk ^ (row & 7)) << 4) + sub)
            = make_uint2(lo, hi);
    }

    f32x4 acc2[16];
    #pragma unroll
    for (int n = 0; n < 16; ++n) acc2[n] = (f32x4){0.f, 0.f, 0.f, 0.f};

    #pragma unroll
    for (int c = 0; c < 4; ++c) {
        // ---- stage 1: interm chunk c (128 cols), 8 n-frags ----
        f32x4 sacc[8];
        #pragma unroll
        for (int n = 0; n < 8; ++n) sacc[n] = (f32x4){0.f, 0.f, 0.f, 0.f};
        #pragma unroll
        for (int ks = 0; ks < 4; ++ks) {
            int kc = (ks * 4 + l4) ^ (l15 & 7);
            s8v af = *(const s8v*)&Ae[l15 * 128 + kc * 8];
            #pragma unroll
            for (int n = 0; n < 8; ++n) {
                int col1 = c * 128 + n * 16 + l15;
                s8v bf = *(const s8v*)(We1T + (size_t)col1 * 128 + ks * 32 + l4 * 8);
                sacc[n] = __builtin_amdgcn_mfma_f32_16x16x32_bf16(af, bf, sacc[n], 0, 0, 0);
            }
        }
        // write interm to private Ic with bias+relu (swizzled chunk layout)
        #pragma unroll
        for (int n = 0; n < 8; ++n) {
            int col = n * 16 + l15;
            float bv = b1[c * 128 + col];
            int chunk = col >> 3, sub = col & 7;
            #pragma unroll
            for (int q = 0; q < 4; ++q) {
                int row = l4 * 4 + q;   // 0..15
                float v = fmaxf(sacc[n][q] + bv, 0.f);
                Ic[row * 128 + ((chunk ^ (row & 7)) << 3) + sub] = f2b(v);
            }
        }
        // ---- stage 2: accumulate all 256 out cols over this K-chunk ----
        #pragma unroll
        for (int ks = 0; ks < 4; ++ks) {
            int kc = (ks * 4 + l4) ^ (l15 & 7);
            s8v af = *(const s8v*)&Ic[l15 * 128 + kc * 8];
            #pragma unroll
            for (int n = 0; n < 16; ++n) {
                int col = n * 16 + l15;
                s8v bf = *(const s8v*)(We2T + (size_t)col * 512 + c * 128 + ks * 32 + l4 * 8);
                acc2[n] = __builtin_amdgcn_mfma_f32_16x16x32_bf16(af, bf, acc2[n], 0, 0, 0);
            }
        }
    }

    // ---- epilogue: bias + f32 store ----
    #pragma unroll
    for (int n = 0; n < 16; ++n) {
        int col = n * 16 + l15;
        float bv = b2[col];
        #pragma unroll
        for (int q = 0; q < 4; ++q) {
            int row = l4 * 4 + q;
            out[(size_t)(r0 + row) * 256 + col] = acc2[n][q] + bv;
        }
    }
}

// =============== weight conversions ===============
// W [K x N] f32 -> WT [N x K] bf16
__global__ __launch_bounds__(256) void transpose_f2b(
    const float* __restrict__ W, u16* __restrict__ WT, int K, int N)
{
    __shared__ float tile[32][33];
    int kb = blockIdx.x * 32, nb = blockIdx.y * 32;
    int tx = threadIdx.x & 31, ty = threadIdx.x >> 5;   // ty 0..7
    #pragma unroll
    for (int i = 0; i < 32; i += 8)
        tile[ty + i][tx] = W[(size_t)(kb + ty + i) * N + nb + tx];
    __syncthreads();
    #pragma unroll
    for (int i = 0; i < 32; i += 8)
        WT[(size_t)(nb + ty + i) * K + kb + tx] = f2b(tile[tx][ty + i]);
}

// Wk[r][h][d][e] -> WkT[h][r*64+e][d]
__global__ void conv_wk(const float* __restrict__ Wk, u16* __restrict__ WkT)
{
    int idx = blockIdx.x * 256 + threadIdx.x;
    if (idx >= 8 * 256 * 64) return;
    int d = idx & 63, re = (idx >> 6) & 255, h = idx >> 14;
    int e = re & 63, r = re >> 6;
    WkT[idx] = f2b(Wk[(size_t)(((r * 8 + h) * 64 + d) * 64) + e]);
}

// Wv[r][h][d][e] -> WvT[h][e][r*64+d]
__global__ void conv_wv(const float* __restrict__ Wv, u16* __restrict__ WvT)
{
    int idx = blockIdx.x * 256 + threadIdx.x;
    if (idx >= 8 * 64 * 256) return;
    int d = idx & 63, r = (idx >> 6) & 3, e = (idx >> 8) & 63, h = idx >> 14;
    WvT[idx] = f2b(Wv[(size_t)(((r * 8 + h) * 64 + d) * 64) + e]);
}

// =============== CSR build ===============
__global__ void deg_kernel(const int* __restrict__ ei, int* __restrict__ rowptr)
{
    int idx = blockIdx.x * 256 + threadIdx.x;
    if (idx >= MEDGE) return;
    int r = idx / EE;
    atomicAdd(&rowptr[ei[idx + (r + 1) * EE]], 1);
}

__global__ __launch_bounds__(256) void scan_kernel(int* __restrict__ rowptr)
{
    __shared__ int buf[256];
    __shared__ int carry;
    const int t = threadIdx.x;
    if (t == 0) carry = 0;
    __syncthreads();
    for (int base = 0; base < NN; base += 256) {
        int i = base + t;
        int v = (i < NN) ? rowptr[i] : 0;
        buf[t] = v;
        __syncthreads();
        for (int off = 1; off < 256; off <<= 1) {
            int tv = (t >= off) ? buf[t - off] : 0;
            __syncthreads();
            buf[t] += tv;
            __syncthreads();
        }
        int total = buf[255];
        int excl = buf[t] - v;
        int c = carry;
        __syncthreads();
        if (i < NN) rowptr[i] = c + excl;
        if (t == 0) carry = c + total;
        __syncthreads();
    }
    if (t == 0) rowptr[NN] = carry;
}

__global__ void fill_kernel(const int* __restrict__ ei, const int* __restrict__ rowptr,
                            int* __restrict__ fillcnt, int* __restrict__ erec)
{
    int idx = blockIdx.x * 256 + threadIdx.x;
    if (idx >= MEDGE) return;
    int r = idx / EE;
    int dst = ei[idx + (r + 1) * EE];
    int pos = rowptr[dst] + atomicAdd(&fillcnt[dst], 1);
    erec[pos] = idx;
}

// =============== fused alpha + online-LSE (all relations; wave per node) ===============
// krel2 layout: [n][h*256 + r*64 + d] bf16 (one 2KB row per src node)
__global__ __launch_bounds__(256) void alpha_stats(
    const u16* __restrict__ krel2, const u16* __restrict__ kqvb,
    const int* __restrict__ ei, const int* __restrict__ rowptr,
    const int* __restrict__ erec, const float* __restrict__ prel,
    float* __restrict__ alpha, float* __restrict__ lse)
{
    int n    = (blockIdx.x * 256 + threadIdx.x) >> 6;
    int lane = threadIdx.x & 63;
    if (n >= NN) return;
    int p0 = rowptr[n], p1 = rowptr[n + 1];
    int h = lane >> 3, sub = lane & 7;
    s8v qv = *(const s8v*)(kqvb + (size_t)n * 1536 + 512 + h * 64 + sub * 8);
    float qf[8];
    #pragma unroll
    for (int q = 0; q < 8; ++q) qf[q] = b2f((u16)qv[q]);
    float m = -3.0e38f, ssum = 0.f;
    for (int j = p0; j < p1; ++j) {
        int idx = erec[j];
        int r = idx / EE;
        int src = ei[idx + r * EE];
        s8v kv = *(const s8v*)(krel2 + (size_t)src * 2048 + h * 256 + r * 64 + sub * 8);
        float s = 0.f;
        #pragma unroll
        for (int q = 0; q < 8; ++q) s += b2f((u16)kv[q]) * qf[q];
        s += __shfl_xor(s, 1);
        s += __shfl_xor(s, 2);
        s += __shfl_xor(s, 4);
        float a = s * prel[r * NH + h] * SCALEF;
        if (sub == 0) alpha[(size_t)idx * 8 + h] = a;
        float mn = fmaxf(m, a);
        ssum = ssum * expf(m - mn) + expf(a - mn);
        m = mn;
    }
    if (sub == 0) lse[(size_t)n * 8 + h] = m + logf(ssum + 1e-16f);
}

// =============== weighted v aggregation (all relations; wave per node; one CSR scan) ===============
// writes wsumH[h][n][r*64 + d] bf16
__global__ __launch_bounds__(256) void wsum_all(
    const u16* __restrict__ kqvb, const float* __restrict__ alpha,
    const float* __restrict__ lse, const int* __restrict__ rowptr,
    const int* __restrict__ erec, const int* __restrict__ ei,
    u16* __restrict__ wsumH)
{
    int n    = (blockIdx.x * 256 + threadIdx.x) >> 6;
    int lane = threadIdx.x & 63;
    if (n >= NN) return;
    int p0 = rowptr[n], p1 = rowptr[n + 1];
    int h = lane >> 3;
    float ls = lse[(size_t)n * 8 + h];
    float a0[8] = {}, a1[8] = {}, a2[8] = {}, a3[8] = {};
    for (int j = p0; j < p1; ++j) {
        int idx = erec[j];
        int r = idx / EE;                 // wave-uniform
        int src = ei[idx + r * EE];
        float w = expf(alpha[(size_t)idx * 8 + h] - ls);
        s8v vv = *(const s8v*)(kqvb + (size_t)src * 1536 + 1024 + lane * 8);
        if (r == 0) {
            #pragma unroll
            for (int q = 0; q < 8; ++q) a0[q] += w * b2f((u16)vv[q]);
        } else if (r == 1) {
            #pragma unroll
            for (int q = 0; q < 8; ++q) a1[q] += w * b2f((u16)vv[q]);
        } else if (r == 2) {
            #pragma unroll
            for (int q = 0; q < 8; ++q) a2[q] += w * b2f((u16)vv[q]);
        } else {
            #pragma unroll
            for (int q = 0; q < 8; ++q) a3[q] += w * b2f((u16)vv[q]);
        }
    }
    u16* base = wsumH + (size_t)h * SZH + (size_t)n * 256 + (lane & 7) * 8;
    s8v o;
    #pragma unroll
    for (int q = 0; q < 8; ++q) o[q] = (short)f2b(a0[q]);
    *(s8v*)(base + 0)   = o;
    #pragma unroll
    for (int q = 0; q < 8; ++q) o[q] = (short)f2b(a1[q]);
    *(s8v*)(base + 64)  = o;
    #pragma unroll
    for (int q = 0; q < 8; ++q) o[q] = (short)f2b(a2[q]);
    *(s8v*)(base + 128) = o;
    #pragma unroll
    for (int q = 0; q < 8; ++q) o[q] = (short)f2b(a3[q]);
    *(s8v*)(base + 192) = o;
}

extern "C" void kernel_launch(void* const* d_in, const int* in_sizes, int n_in,
                              void* d_out, int out_size, void* d_ws, size_t ws_size,
                              hipStream_t stream)
{
    const float* x    = (const float*)d_in[0];
    const int*   ei   = (const int*)d_in[1];
    const float* ea   = (const float*)d_in[2];
    const float* Wkqv[2] = {(const float*)d_in[3],  (const float*)d_in[10]};
    const float* bkqv[2] = {(const float*)d_in[4],  (const float*)d_in[11]};
    const float* Wk[2]   = {(const float*)d_in[5],  (const float*)d_in[12]};
    const float* Wv[2]   = {(const float*)d_in[6],  (const float*)d_in[13]};
    const float* prel[2] = {(const float*)d_in[7],  (const float*)d_in[14]};
    const float* Wout[2] = {(const float*)d_in[8],  (const float*)d_in[15]};
    const float* bout[2] = {(const float*)d_in[9],  (const float*)d_in[16]};
    const float* skip1 = (const float*)d_in[17];
    const float* Wfc   = (const float*)d_in[18];
    const float* bfc   = (const float*)d_in[19];
    const float* We1   = (const float*)d_in[20];
    const float* be1   = (const float*)d_in[21];
    const float* We2   = (const float*)d_in[22];
    const float* be2   = (const float*)d_in[23];

    if (ws_size < WS_NEED) return;

    char* wsb = (char*)d_ws;
    u16*   kqvb  = (u16*)(wsb + B_KQV);
    u16*   krel2 = (u16*)(wsb + B_KREL);
    u16*   wsumH = krel2;                    // overlay (krel dead after alpha_stats)
    u16*   aggb  = (u16*)(wsb + B_AGG);
    u16*   h0b   = (u16*)(wsb + B_H0);
    u16*   h1b   = (u16*)(wsb + B_H1);
    float* alpha = (float*)(wsb + B_ALPHA);
    float* lse   = (float*)(wsb + B_LSE);
    int*   fillcnt = (int*)(wsb + B_LSE);    // build-time overlay
    int*   rowptr  = (int*)(wsb + B_ROWP);
    int*   erec    = (int*)(wsb + B_EREC);
    float* outf  = (float*)d_out;

    // bf16 weight arena
    u16* wt = (u16*)(wsb + B_WTS);
    u16* WkqvT[2] = {wt, wt + 393216};              wt += 393216 + 786432;
    u16* WkT[2]   = {wt, wt + 131072};              wt += 262144;
    u16* WvT[2]   = {wt, wt + 131072};              wt += 262144;
    u16* WoutT[2] = {wt, wt + 262144};              wt += 524288;
    u16* WfcT     = wt;                             wt += 131072;
    u16* We1T     = wt;                             wt += 65536;
    u16* We2T     = wt;

    const dim3 blk(256);
    const int mt128  = (NN + 127) / 128;   // 157

    // ---- weight conversions ----
    transpose_f2b<<<dim3(CIN / 32, 1536 / 32), blk, 0, stream>>>(Wkqv[0], WkqvT[0], CIN, 1536);
    transpose_f2b<<<dim3(HIDW / 32, 1536 / 32), blk, 0, stream>>>(Wkqv[1], WkqvT[1], HIDW, 1536);
    transpose_f2b<<<dim3(HIDW / 32, HIDW / 32), blk, 0, stream>>>(Wout[0], WoutT[0], HIDW, HIDW);
    transpose_f2b<<<dim3(HIDW / 32, HIDW / 32), blk, 0, stream>>>(Wout[1], WoutT[1], HIDW, HIDW);
    transpose_f2b<<<dim3(HIDW / 32, OUTW / 32), blk, 0, stream>>>(Wfc, WfcT, HIDW, OUTW);
    transpose_f2b<<<dim3(CEDGE / 32, HIDW / 32), blk, 0, stream>>>(We1, We1T, CEDGE, HIDW);
    transpose_f2b<<<dim3(HIDW / 32, OUTW / 32), blk, 0, stream>>>(We2, We2T, HIDW, OUTW);
    for (int l = 0; l < 2; ++l) {
        conv_wk<<<(131072 + 255) / 256, blk, 0, stream>>>(Wk[l], WkT[l]);
        conv_wv<<<(131072 + 255) / 256, blk, 0, stream>>>(Wv[l], WvT[l]);
    }

    // ---- CSR build ----
    hipMemsetAsync(rowptr, 0, (NN + 1) * sizeof(int), stream);
    hipMemsetAsync(fillcnt, 0, NN * sizeof(int), stream);
    deg_kernel<<<(MEDGE + 255) / 256, blk, 0, stream>>>(ei, rowptr);
    scan_kernel<<<1, blk, 0, stream>>>(rowptr);
    fill_kernel<<<(MEDGE + 255) / 256, blk, 0, stream>>>(ei, rowptr, fillcnt, erec);

    for (int l = 0; l < 2; ++l) {
        int K = (l == 0) ? CIN : HIDW;

        // kqv = xin @ Wkqv + b  -> bf16 [20000 x 1536]   (layer 0 reads f32 x directly)
        if (l == 0)
            gemm_bf16<128, 0, true, true, false, true><<<dim3(12, mt128), blk, 0, stream>>>(
                (const void*)x, K, 0, WkqvT[0], K, 0, bkqv[0], kqvb, 1536, 0, NN, K, nullptr, nullptr);
        else
            gemm_bf16<128, 0, true, true, false><<<dim3(12, mt128), blk, 0, stream>>>(
                (const void*)h0b, K, 0, WkqvT[1], K, 0, bkqv[1], kqvb, 1536, 0, NN, K, nullptr, nullptr);

        // k_rel (all relations): per-head batched GEMM, K=64, N=256; out [n][h*256+r*64+e]
        gemm_bf16<128, 0, true, false, false><<<dim3(2, mt128, NH), blk, 0, stream>>>(
            (const void*)kqvb, 1536, 64, WkT[l], 64, (size_t)256 * 64, nullptr,
            krel2, 2048, 256, NN, 64, nullptr, nullptr);

        alpha_stats<<<(NN * 64) / 256, blk, 0, stream>>>(
            krel2, kqvb, ei, rowptr, erec, prel[l], alpha, lse);

        wsum_all<<<(NN * 64) / 256, blk, 0, stream>>>(
            kqvb, alpha, lse, rowptr, erec, ei, wsumH);

        // agg = gelu( sum_r wsum_r @ Wv_r ) : per-head batched GEMM, K=256, N=64
        gemm_bf16<64, 2, true, false, false><<<dim3(1, mt128, NH), blk, 0, stream>>>(
            (const void*)wsumH, 256, SZH, WvT[l], 256, (size_t)64 * 256, nullptr,
            aggb, 512, 64, NN, 256, nullptr, nullptr);

        // out = agg @ Wout + bout (+ skip mix on layer 1)
        if (l == 0)
            gemm_bf16<128, 0, true, true, false><<<dim3(4, mt128), blk, 0, stream>>>(
                (const void*)aggb, 512, 0, WoutT[0], 512, 0, bout[0], h0b, 512, 0, NN, 512, nullptr, nullptr);
        else
            gemm_bf16<128, 0, true, true, true><<<dim3(4, mt128), blk, 0, stream>>>(
                (const void*)aggb, 512, 0, WoutT[1], 512, 0, bout[1], h1b, 512, 0, NN, 512, h0b, skip1);
    }

    // node_embeds = h1 @ Wfc + bfc (f32 out)
    gemm_bf16<128, 0, false, true, false><<<dim3(2, mt128), blk, 0, stream>>>(
        (const void*)h1b, 512, 0, WfcT, 512, 0, bfc, outf, 256, 0, NN, 512, nullptr, nullptr);

    // edge_embeds = relu(ea @ We1 + be1) @ We2 + be2 — wave-private fused, zero barriers
    edge_mlp<<<MEDGE / 64, blk, 0, stream>>>(ea, We1T, be1, We2T, be2, outf + 5120000);
}

// Round 9
// 762.564 us; speedup vs baseline: 1.4133x; 1.4133x over previous
//
#include <hip/hip_runtime.h>
#include <cstdint>
#include <cstddef>

#define NN      20000
#define RR      4
#define EE      40000
#define CIN     256
#define CEDGE   128
#define HIDW    512
#define OUTW    256
#define NH      8
#define MEDGE   (RR*EE)
#define SCALEF  0.125f

typedef unsigned short u16;
typedef short s8v  __attribute__((ext_vector_type(8)));
typedef float f32x4 __attribute__((ext_vector_type(4)));

// ---- ws layout (BYTE offsets) ----
#define B_KQV   10240000ull             // 20000*1536*2 = 61,440,000
#define B_KREL  71680000ull             // 20000*2048*2 = 81,920,000 (wsumH overlays after alpha)
#define B_AGG   153600000ull            // 20000*512*2
#define B_H0    174080000ull            // 20000*512*2
#define B_H1    194560000ull            // 20000*512*2
#define B_ALPHA 215040000ull            // 160000*8*4 = 5,120,000 (f32)
#define B_LSE   220160000ull            // 20000*8*4 (f32); fillcnt overlay during CSR build
#define B_ROWP  220800000ull            // 20001*4 -> pad
#define B_EREC  220880128ull            // 160000*4
#define B_WTS   221520128ull            // bf16 weights, ~5.2 MB
#define WS_NEED 227000000ull

#define SZH ((size_t)NN * 256)          // elements per head-matrix (wsumH)

__device__ __forceinline__ u16 f2b(float f) {
    unsigned u = __float_as_uint(f);
    unsigned r = (u + 0x7FFFu + ((u >> 16) & 1u)) >> 16;
    return (u16)r;
}
__device__ __forceinline__ float b2f(u16 h) { return __uint_as_float(((unsigned)h) << 16); }
__device__ __forceinline__ float gelu_exact(float x) {
    return 0.5f * x * (1.0f + erff(x * 0.70710678118654752f));
}

// async global->LDS, 16 bytes per lane; LDS dest must be wave-uniform base
__device__ __forceinline__ void gl_lds16(const u16* g, u16* l) {
    __builtin_amdgcn_global_load_lds(
        (const __attribute__((address_space(1))) void*)g,
        (__attribute__((address_space(3))) void*)l, 16, 0, 0);
}

// =============== generic bf16 MFMA GEMM (R6 single-buffered version, proven) ===============
// A: M x K row-major (lda) — bf16, or f32 converted during staging when AF32.
// BT: N x K bf16 row-major (ldb). C: M x N (ldc). batched over blockIdx.z via strides.
// K%64==0, N%BN==0, M guarded (rows clamped on load).
// LDS layout: As[row][chunk] (chunk = 8 elems / 16B) holds global chunk (chunk ^ (row&7)).
// ACT: 0 none, 1 relu, 2 gelu. SKIP: out = g*out+(1-g)*skipx (bf16).
template<int BN, int ACT, bool OUTBF16, bool BIAS, bool SKIP, bool AF32 = false>
__global__ __launch_bounds__(256) void gemm_bf16(
    const void* __restrict__ Av, int lda, size_t astride,
    const u16* __restrict__ BT, int ldb, size_t bstride,
    const float* __restrict__ bias,
    void* __restrict__ Cv, int ldc, size_t cstride,
    int M, int K,
    const u16* __restrict__ skipx, const float* __restrict__ gatep)
{
    constexpr int FN = BN / 32;         // frags per wave along N (wave covers BN/2)
    constexpr int BI = BN / 32;         // B stage instructions per wave
    __shared__ __align__(16) u16 As[128 * 64];
    __shared__ __align__(16) u16 Bs[BN * 64];

    const int t = threadIdx.x, lane = t & 63, wid = t >> 6;
    const int m0 = blockIdx.y * 128, n0 = blockIdx.x * BN;
    const int z  = blockIdx.z;
    const u16*   Bz = BT + (size_t)z * bstride;
    const float* Af = (const float*)Av + (AF32 ? (size_t)z * astride : 0);
    const u16*   Au = (const u16*)Av   + (AF32 ? 0 : (size_t)z * astride);
    const int wm = wid >> 1, wn = wid & 1;

    // per-lane staging constants: lane covers row-in-group (lane>>3), swizzled k-chunk
    const int srow   = lane >> 3;
    const int schunk = (lane & 7) ^ srow;

    f32x4 acc[4][FN];
    #pragma unroll
    for (int i = 0; i < 4; ++i)
        #pragma unroll
        for (int j = 0; j < FN; ++j)
            acc[i][j] = (f32x4){0.f, 0.f, 0.f, 0.f};

    for (int k0 = 0; k0 < K; k0 += 64) {
        if (AF32) {
            // reg staging with f32->bf16 convert; write to swizzled chunk
            #pragma unroll
            for (int i = 0; i < 4; ++i) {
                int c = i * 256 + t;
                int row = c >> 3, cc = c & 7;
                int gr = m0 + row; gr = gr < M ? gr : M - 1;
                const float* Ap = Af + (size_t)gr * lda + k0 + cc * 8;
                float4 p = *(const float4*)Ap;
                float4 q = *(const float4*)(Ap + 4);
                s8v v;
                v[0] = (short)f2b(p.x); v[1] = (short)f2b(p.y);
                v[2] = (short)f2b(p.z); v[3] = (short)f2b(p.w);
                v[4] = (short)f2b(q.x); v[5] = (short)f2b(q.y);
                v[6] = (short)f2b(q.z); v[7] = (short)f2b(q.w);
                *(s8v*)&As[row * 64 + ((cc ^ (row & 7)) << 3)] = v;
            }
        } else {
            // async staging: 16 wave-instructions cover 128 rows x 64 k
            #pragma unroll
            for (int i = 0; i < 4; ++i) {
                int t4 = wid * 4 + i;
                int row = t4 * 8 + srow;
                int gr = m0 + row; gr = gr < M ? gr : M - 1;
                gl_lds16(Au + (size_t)gr * lda + k0 + schunk * 8, &As[t4 * 512]);
            }
        }
        #pragma unroll
        for (int i = 0; i < BI; ++i) {
            int tb = wid * BI + i;
            int col = n0 + tb * 8 + srow;
            gl_lds16(Bz + (size_t)col * ldb + k0 + schunk * 8, &Bs[tb * 512]);
        }
        __syncthreads();   // drains vmcnt (incl. global_load_lds) + lgkmcnt
        #pragma unroll
        for (int ks = 0; ks < 2; ++ks) {
            s8v af[4], bf[FN];
            #pragma unroll
            for (int i = 0; i < 4; ++i) {
                int arow = wm * 64 + i * 16 + (lane & 15);
                int ac   = (ks * 4 + (lane >> 4)) ^ (lane & 7);
                af[i] = *(const s8v*)&As[arow * 64 + ac * 8];
            }
            #pragma unroll
            for (int j = 0; j < FN; ++j) {
                int brow = wn * (BN / 2) + j * 16 + (lane & 15);
                int bc   = (ks * 4 + (lane >> 4)) ^ (lane & 7);
                bf[j] = *(const s8v*)&Bs[brow * 64 + bc * 8];
            }
            #pragma unroll
            for (int i = 0; i < 4; ++i)
                #pragma unroll
                for (int j = 0; j < FN; ++j)
                    acc[i][j] = __builtin_amdgcn_mfma_f32_16x16x32_bf16(af[i], bf[j], acc[i][j], 0, 0, 0);
        }
        __syncthreads();
    }

    float gate = 1.f, ogate = 0.f;
    if (SKIP) { float s = *gatep; gate = 1.f / (1.f + expf(-s)); ogate = 1.f - gate; }
    u16*   Cb = (u16*)Cv   + (size_t)z * cstride;
    float* Cf = (float*)Cv + (size_t)z * cstride;
    #pragma unroll
    for (int i = 0; i < 4; ++i) {
        int rbase = m0 + wm * 64 + i * 16 + (lane >> 4) * 4;
        #pragma unroll
        for (int j = 0; j < FN; ++j) {
            int col = n0 + wn * (BN / 2) + j * 16 + (lane & 15);
            float bv = BIAS ? bias[col] : 0.f;
            #pragma unroll
            for (int q = 0; q < 4; ++q) {
                int r = rbase + q;
                if (r >= M) continue;
                float v = acc[i][j][q] + bv;
                if (ACT == 1) v = fmaxf(v, 0.f);
                if (ACT == 2) v = gelu_exact(v);
                if (SKIP) v = gate * v + ogate * b2f(skipx[(size_t)r * ldc + col]);
                if (OUTBF16) Cb[(size_t)r * ldc + col] = f2b(v);
                else         Cf[(size_t)r * ldc + col] = v;
            }
        }
    }
}

// =============== fused edge MLP v4 — 128 rows, 8 waves, shared tiles ===============
// out = relu(ea @ We1 + b1) @ We2 + b2. Interm never leaves LDS.
// Per interm chunk c (128 cols): stage 1 — wave owns 16 interm cols (1 n-frag,
// 4 B loads, 32 MFMA); stage 2 — wave owns 32 out cols (2 n-frags, 8 B loads, 64 MFMA).
// 2x better B amortization than the 64-row version; W1(c+1) prefetched into regs.
__global__ __launch_bounds__(512) void edge_mlp(
    const float* __restrict__ ea, const u16* __restrict__ We1T,
    const float* __restrict__ b1, const u16* __restrict__ We2T,
    const float* __restrict__ b2, float* __restrict__ out)
{
    __shared__ __align__(16) u16 Ae[128 * 128];
    __shared__ __align__(16) u16 Ic[128 * 128];

    const int t = threadIdx.x, lane = t & 63, w = t >> 6;   // w 0..7
    const int e0 = blockIdx.x * 128;
    const int l15 = lane & 15, l4 = lane >> 4;

    s8v w1f[4];   // stage-1 B frags for current chunk (wave's 16 cols x K-slice ks)
    auto loadW1 = [&](s8v* dst, int c) {
        #pragma unroll
        for (int ks = 0; ks < 4; ++ks) {
            int col1 = c * 128 + w * 16 + l15;
            dst[ks] = *(const s8v*)(We1T + (size_t)col1 * 128 + ks * 32 + l4 * 8);
        }
    };
    loadW1(w1f, 0);   // in flight during ea staging

    // ---- stage ea tile: 128 rows x 128 f32 -> bf16, chunk-XOR swizzle ----
    #pragma unroll
    for (int i = 0; i < 8; ++i) {
        int f   = i * 512 + t;          // float4 index 0..4095
        int row = f >> 5;               // 0..127
        int c4  = f & 31;               // float4 within row
        float4 p = *(const float4*)(ea + (size_t)(e0 + row) * 128 + c4 * 4);
        unsigned lo = (unsigned)f2b(p.x) | ((unsigned)f2b(p.y) << 16);
        unsigned hi = (unsigned)f2b(p.z) | ((unsigned)f2b(p.w) << 16);
        int chunk = c4 >> 1;            // 16B chunk 0..15
        int sub   = (c4 & 1) * 8;       // byte offset within chunk
        *(uint2*)((char*)Ae + row * 256 + ((chunk ^ (row & 7)) << 4) + sub)
            = make_uint2(lo, hi);
    }
    __syncthreads();

    f32x4 acc2[8][2];
    #pragma unroll
    for (int m = 0; m < 8; ++m) {
        acc2[m][0] = (f32x4){0.f, 0.f, 0.f, 0.f};
        acc2[m][1] = (f32x4){0.f, 0.f, 0.f, 0.f};
    }

    #pragma unroll
    for (int c = 0; c < 4; ++c) {
        // ---- stage 1: interm cols [w*16, w*16+16) of chunk c ----
        f32x4 sacc[8];
        #pragma unroll
        for (int m = 0; m < 8; ++m) sacc[m] = (f32x4){0.f, 0.f, 0.f, 0.f};
        #pragma unroll
        for (int ks = 0; ks < 4; ++ks) {
            #pragma unroll
            for (int m = 0; m < 8; ++m) {
                int row = m * 16 + l15;
                int kc  = (ks * 4 + l4) ^ (row & 7);
                s8v af = *(const s8v*)&Ae[row * 128 + kc * 8];
                sacc[m] = __builtin_amdgcn_mfma_f32_16x16x32_bf16(af, w1f[ks], sacc[m], 0, 0, 0);
            }
        }
        // issue stage-2 B loads now: latency hides under barrier + Ic writes
        s8v w2f[4][2];
        #pragma unroll
        for (int ks = 0; ks < 4; ++ks)
            #pragma unroll
            for (int n = 0; n < 2; ++n) {
                int col = w * 32 + n * 16 + l15;
                w2f[ks][n] = *(const s8v*)(We2T + (size_t)col * 512 + c * 128 + ks * 32 + l4 * 8);
            }
        __syncthreads();   // all waves done with stage-2 reads of previous Ic
        // write interm (bias+relu) to shared Ic, swizzled chunk layout
        {
            int col = w * 16 + l15;
            float bv = b1[c * 128 + col];
            int chunk = col >> 3, sub = col & 7;
            #pragma unroll
            for (int m = 0; m < 8; ++m)
                #pragma unroll
                for (int q = 0; q < 4; ++q) {
                    int row = m * 16 + l4 * 4 + q;
                    float v = fmaxf(sacc[m][q] + bv, 0.f);
                    Ic[row * 128 + ((chunk ^ (row & 7)) << 3) + sub] = f2b(v);
                }
        }
        if (c < 3) loadW1(w1f, c + 1);   // prefetch next chunk's stage-1 B
        __syncthreads();
        // ---- stage 2: out cols [w*32, w*32+32), accumulate over this K-chunk ----
        #pragma unroll
        for (int ks = 0; ks < 4; ++ks) {
            #pragma unroll
            for (int m = 0; m < 8; ++m) {
                int row = m * 16 + l15;
                int kc  = (ks * 4 + l4) ^ (row & 7);
                s8v af = *(const s8v*)&Ic[row * 128 + kc * 8];
                acc2[m][0] = __builtin_amdgcn_mfma_f32_16x16x32_bf16(af, w2f[ks][0], acc2[m][0], 0, 0, 0);
                acc2[m][1] = __builtin_amdgcn_mfma_f32_16x16x32_bf16(af, w2f[ks][1], acc2[m][1], 0, 0, 0);
            }
        }
    }

    // ---- epilogue: bias + f32 store (wave's 32 cols x 128 rows) ----
    #pragma unroll
    for (int n = 0; n < 2; ++n) {
        int col = w * 32 + n * 16 + l15;
        float bv = b2[col];
        #pragma unroll
        for (int m = 0; m < 8; ++m)
            #pragma unroll
            for (int q = 0; q < 4; ++q) {
                int row = m * 16 + l4 * 4 + q;
                out[(size_t)(e0 + row) * 256 + col] = acc2[m][n][q] + bv;
            }
    }
}

// =============== weight conversions ===============
// W [K x N] f32 -> WT [N x K] bf16
__global__ __launch_bounds__(256) void transpose_f2b(
    const float* __restrict__ W, u16* __restrict__ WT, int K, int N)
{
    __shared__ float tile[32][33];
    int kb = blockIdx.x * 32, nb = blockIdx.y * 32;
    int tx = threadIdx.x & 31, ty = threadIdx.x >> 5;   // ty 0..7
    #pragma unroll
    for (int i = 0; i < 32; i += 8)
        tile[ty + i][tx] = W[(size_t)(kb + ty + i) * N + nb + tx];
    __syncthreads();
    #pragma unroll
    for (int i = 0; i < 32; i += 8)
        WT[(size_t)(nb + ty + i) * K + kb + tx] = f2b(tile[tx][ty + i]);
}

// Wk[r][h][d][e] -> WkT[h][r*64+e][d]
__global__ void conv_wk(const float* __restrict__ Wk, u16* __restrict__ WkT)
{
    int idx = blockIdx.x * 256 + threadIdx.x;
    if (idx >= 8 * 256 * 64) return;
    int d = idx & 63, re = (idx >> 6) & 255, h = idx >> 14;
    int e = re & 63, r = re >> 6;
    WkT[idx] = f2b(Wk[(size_t)(((r * 8 + h) * 64 + d) * 64) + e]);
}

// Wv[r][h][d][e] -> WvT[h][e][r*64+d]
__global__ void conv_wv(const float* __restrict__ Wv, u16* __restrict__ WvT)
{
    int idx = blockIdx.x * 256 + threadIdx.x;
    if (idx >= 8 * 64 * 256) return;
    int d = idx & 63, r = (idx >> 6) & 3, e = (idx >> 8) & 63, h = idx >> 14;
    WvT[idx] = f2b(Wv[(size_t)(((r * 8 + h) * 64 + d) * 64) + e]);
}

// =============== CSR build ===============
__global__ void deg_kernel(const int* __restrict__ ei, int* __restrict__ rowptr)
{
    int idx = blockIdx.x * 256 + threadIdx.x;
    if (idx >= MEDGE) return;
    int r = idx / EE;
    atomicAdd(&rowptr[ei[idx + (r + 1) * EE]], 1);
}

__global__ __launch_bounds__(256) void scan_kernel(int* __restrict__ rowptr)
{
    __shared__ int buf[256];
    __shared__ int carry;
    const int t = threadIdx.x;
    if (t == 0) carry = 0;
    __syncthreads();
    for (int base = 0; base < NN; base += 256) {
        int i = base + t;
        int v = (i < NN) ? rowptr[i] : 0;
        buf[t] = v;
        __syncthreads();
        for (int off = 1; off < 256; off <<= 1) {
            int tv = (t >= off) ? buf[t - off] : 0;
            __syncthreads();
            buf[t] += tv;
            __syncthreads();
        }
        int total = buf[255];
        int excl = buf[t] - v;
        int c = carry;
        __syncthreads();
        if (i < NN) rowptr[i] = c + excl;
        if (t == 0) carry = c + total;
        __syncthreads();
    }
    if (t == 0) rowptr[NN] = carry;
}

__global__ void fill_kernel(const int* __restrict__ ei, const int* __restrict__ rowptr,
                            int* __restrict__ fillcnt, int* __restrict__ erec)
{
    int idx = blockIdx.x * 256 + threadIdx.x;
    if (idx >= MEDGE) return;
    int r = idx / EE;
    int dst = ei[idx + (r + 1) * EE];
    int pos = rowptr[dst] + atomicAdd(&fillcnt[dst], 1);
    erec[pos] = idx;
}

// =============== fused alpha + online-LSE (all relations; wave per node) ===============
// krel2 layout: [n][h*256 + r*64 + d] bf16 (one 2KB row per src node)
__global__ __launch_bounds__(256) void alpha_stats(
    const u16* __restrict__ krel2, const u16* __restrict__ kqvb,
    const int* __restrict__ ei, const int* __restrict__ rowptr,
    const int* __restrict__ erec, const float* __restrict__ prel,
    float* __restrict__ alpha, float* __restrict__ lse)
{
    int n    = (blockIdx.x * 256 + threadIdx.x) >> 6;
    int lane = threadIdx.x & 63;
    if (n >= NN) return;
    int p0 = rowptr[n], p1 = rowptr[n + 1];
    int h = lane >> 3, sub = lane & 7;
    s8v qv = *(const s8v*)(kqvb + (size_t)n * 1536 + 512 + h * 64 + sub * 8);
    float qf[8];
    #pragma unroll
    for (int q = 0; q < 8; ++q) qf[q] = b2f((u16)qv[q]);
    float m = -3.0e38f, ssum = 0.f;
    for (int j = p0; j < p1; ++j) {
        int idx = erec[j];
        int r = idx / EE;
        int src = ei[idx + r * EE];
        s8v kv = *(const s8v*)(krel2 + (size_t)src * 2048 + h * 256 + r * 64 + sub * 8);
        float s = 0.f;
        #pragma unroll
        for (int q = 0; q < 8; ++q) s += b2f((u16)kv[q]) * qf[q];
        s += __shfl_xor(s, 1);
        s += __shfl_xor(s, 2);
        s += __shfl_xor(s, 4);
        float a = s * prel[r * NH + h] * SCALEF;
        if (sub == 0) alpha[(size_t)idx * 8 + h] = a;
        float mn = fmaxf(m, a);
        ssum = ssum * expf(m - mn) + expf(a - mn);
        m = mn;
    }
    if (sub == 0) lse[(size_t)n * 8 + h] = m + logf(ssum + 1e-16f);
}

// =============== weighted v aggregation (all relations; wave per node; one CSR scan) ===============
// writes wsumH[h][n][r*64 + d] bf16
__global__ __launch_bounds__(256) void wsum_all(
    const u16* __restrict__ kqvb, const float* __restrict__ alpha,
    const float* __restrict__ lse, const int* __restrict__ rowptr,
    const int* __restrict__ erec, const int* __restrict__ ei,
    u16* __restrict__ wsumH)
{
    int n    = (blockIdx.x * 256 + threadIdx.x) >> 6;
    int lane = threadIdx.x & 63;
    if (n >= NN) return;
    int p0 = rowptr[n], p1 = rowptr[n + 1];
    int h = lane >> 3;
    float ls = lse[(size_t)n * 8 + h];
    float a0[8] = {}, a1[8] = {}, a2[8] = {}, a3[8] = {};
    for (int j = p0; j < p1; ++j) {
        int idx = erec[j];
        int r = idx / EE;                 // wave-uniform
        int src = ei[idx + r * EE];
        float w = expf(alpha[(size_t)idx * 8 + h] - ls);
        s8v vv = *(const s8v*)(kqvb + (size_t)src * 1536 + 1024 + lane * 8);
        if (r == 0) {
            #pragma unroll
            for (int q = 0; q < 8; ++q) a0[q] += w * b2f((u16)vv[q]);
        } else if (r == 1) {
            #pragma unroll
            for (int q = 0; q < 8; ++q) a1[q] += w * b2f((u16)vv[q]);
        } else if (r == 2) {
            #pragma unroll
            for (int q = 0; q < 8; ++q) a2[q] += w * b2f((u16)vv[q]);
        } else {
            #pragma unroll
            for (int q = 0; q < 8; ++q) a3[q] += w * b2f((u16)vv[q]);
        }
    }
    u16* base = wsumH + (size_t)h * SZH + (size_t)n * 256 + (lane & 7) * 8;
    s8v o;
    #pragma unroll
    for (int q = 0; q < 8; ++q) o[q] = (short)f2b(a0[q]);
    *(s8v*)(base + 0)   = o;
    #pragma unroll
    for (int q = 0; q < 8; ++q) o[q] = (short)f2b(a1[q]);
    *(s8v*)(base + 64)  = o;
    #pragma unroll
    for (int q = 0; q < 8; ++q) o[q] = (short)f2b(a2[q]);
    *(s8v*)(base + 128) = o;
    #pragma unroll
    for (int q = 0; q < 8; ++q) o[q] = (short)f2b(a3[q]);
    *(s8v*)(base + 192) = o;
}

extern "C" void kernel_launch(void* const* d_in, const int* in_sizes, int n_in,
                              void* d_out, int out_size, void* d_ws, size_t ws_size,
                              hipStream_t stream)
{
    const float* x    = (const float*)d_in[0];
    const int*   ei   = (const int*)d_in[1];
    const float* ea   = (const float*)d_in[2];
    const float* Wkqv[2] = {(const float*)d_in[3],  (const float*)d_in[10]};
    const float* bkqv[2] = {(const float*)d_in[4],  (const float*)d_in[11]};
    const float* Wk[2]   = {(const float*)d_in[5],  (const float*)d_in[12]};
    const float* Wv[2]   = {(const float*)d_in[6],  (const float*)d_in[13]};
    const float* prel[2] = {(const float*)d_in[7],  (const float*)d_in[14]};
    const float* Wout[2] = {(const float*)d_in[8],  (const float*)d_in[15]};
    const float* bout[2] = {(const float*)d_in[9],  (const float*)d_in[16]};
    const float* skip1 = (const float*)d_in[17];
    const float* Wfc   = (const float*)d_in[18];
    const float* bfc   = (const float*)d_in[19];
    const float* We1   = (const float*)d_in[20];
    const float* be1   = (const float*)d_in[21];
    const float* We2   = (const float*)d_in[22];
    const float* be2   = (const float*)d_in[23];

    if (ws_size < WS_NEED) return;

    char* wsb = (char*)d_ws;
    u16*   kqvb  = (u16*)(wsb + B_KQV);
    u16*   krel2 = (u16*)(wsb + B_KREL);
    u16*   wsumH = krel2;                    // overlay (krel dead after alpha_stats)
    u16*   aggb  = (u16*)(wsb + B_AGG);
    u16*   h0b   = (u16*)(wsb + B_H0);
    u16*   h1b   = (u16*)(wsb + B_H1);
    float* alpha = (float*)(wsb + B_ALPHA);
    float* lse   = (float*)(wsb + B_LSE);
    int*   fillcnt = (int*)(wsb + B_LSE);    // build-time overlay
    int*   rowptr  = (int*)(wsb + B_ROWP);
    int*   erec    = (int*)(wsb + B_EREC);
    float* outf  = (float*)d_out;

    // bf16 weight arena
    u16* wt = (u16*)(wsb + B_WTS);
    u16* WkqvT[2] = {wt, wt + 393216};              wt += 393216 + 786432;
    u16* WkT[2]   = {wt, wt + 131072};              wt += 262144;
    u16* WvT[2]   = {wt, wt + 131072};              wt += 262144;
    u16* WoutT[2] = {wt, wt + 262144};              wt += 524288;
    u16* WfcT     = wt;                             wt += 131072;
    u16* We1T     = wt;                             wt += 65536;
    u16* We2T     = wt;

    const dim3 blk(256);
    const int mt128  = (NN + 127) / 128;   // 157

    // ---- weight conversions ----
    transpose_f2b<<<dim3(CIN / 32, 1536 / 32), blk, 0, stream>>>(Wkqv[0], WkqvT[0], CIN, 1536);
    transpose_f2b<<<dim3(HIDW / 32, 1536 / 32), blk, 0, stream>>>(Wkqv[1], WkqvT[1], HIDW, 1536);
    transpose_f2b<<<dim3(HIDW / 32, HIDW / 32), blk, 0, stream>>>(Wout[0], WoutT[0], HIDW, HIDW);
    transpose_f2b<<<dim3(HIDW / 32, HIDW / 32), blk, 0, stream>>>(Wout[1], WoutT[1], HIDW, HIDW);
    transpose_f2b<<<dim3(HIDW / 32, OUTW / 32), blk, 0, stream>>>(Wfc, WfcT, HIDW, OUTW);
    transpose_f2b<<<dim3(CEDGE / 32, HIDW / 32), blk, 0, stream>>>(We1, We1T, CEDGE, HIDW);
    transpose_f2b<<<dim3(HIDW / 32, OUTW / 32), blk, 0, stream>>>(We2, We2T, HIDW, OUTW);
    for (int l = 0; l < 2; ++l) {
        conv_wk<<<(131072 + 255) / 256, blk, 0, stream>>>(Wk[l], WkT[l]);
        conv_wv<<<(131072 + 255) / 256, blk, 0, stream>>>(Wv[l], WvT[l]);
    }

    // ---- CSR build ----
    hipMemsetAsync(rowptr, 0, (NN + 1) * sizeof(int), stream);
    hipMemsetAsync(fillcnt, 0, NN * sizeof(int), stream);
    deg_kernel<<<(MEDGE + 255) / 256, blk, 0, stream>>>(ei, rowptr);
    scan_kernel<<<1, blk, 0, stream>>>(rowptr);
    fill_kernel<<<(MEDGE + 255) / 256, blk, 0, stream>>>(ei, rowptr, fillcnt, erec);

    for (int l = 0; l < 2; ++l) {
        int K = (l == 0) ? CIN : HIDW;

        // kqv = xin @ Wkqv + b  -> bf16 [20000 x 1536]   (layer 0 reads f32 x directly)
        if (l == 0)
            gemm_bf16<128, 0, true, true, false, true><<<dim3(12, mt128), blk, 0, stream>>>(
                (const void*)x, K, 0, WkqvT[0], K, 0, bkqv[0], kqvb, 1536, 0, NN, K, nullptr, nullptr);
        else
            gemm_bf16<128, 0, true, true, false><<<dim3(12, mt128), blk, 0, stream>>>(
                (const void*)h0b, K, 0, WkqvT[1], K, 0, bkqv[1], kqvb, 1536, 0, NN, K, nullptr, nullptr);

        // k_rel (all relations): per-head batched GEMM, K=64, N=256; out [n][h*256+r*64+e]
        gemm_bf16<128, 0, true, false, false><<<dim3(2, mt128, NH), blk, 0, stream>>>(
            (const void*)kqvb, 1536, 64, WkT[l], 64, (size_t)256 * 64, nullptr,
            krel2, 2048, 256, NN, 64, nullptr, nullptr);

        alpha_stats<<<(NN * 64) / 256, blk, 0, stream>>>(
            krel2, kqvb, ei, rowptr, erec, prel[l], alpha, lse);

        wsum_all<<<(NN * 64) / 256, blk, 0, stream>>>(
            kqvb, alpha, lse, rowptr, erec, ei, wsumH);

        // agg = gelu( sum_r wsum_r @ Wv_r ) : per-head batched GEMM, K=256, N=64
        gemm_bf16<64, 2, true, false, false><<<dim3(1, mt128, NH), blk, 0, stream>>>(
            (const void*)wsumH, 256, SZH, WvT[l], 256, (size_t)64 * 256, nullptr,
            aggb, 512, 64, NN, 256, nullptr, nullptr);

        // out = agg @ Wout + bout (+ skip mix on layer 1)
        if (l == 0)
            gemm_bf16<128, 0, true, true, false><<<dim3(4, mt128), blk, 0, stream>>>(
                (const void*)aggb, 512, 0, WoutT[0], 512, 0, bout[0], h0b, 512, 0, NN, 512, nullptr, nullptr);
        else
            gemm_bf16<128, 0, true, true, true><<<dim3(4, mt128), blk, 0, stream>>>(
                (const void*)aggb, 512, 0, WoutT[1], 512, 0, bout[1], h1b, 512, 0, NN, 512, h0b, skip1);
    }

    // node_embeds = h1 @ Wfc + bfc (f32 out)
    gemm_bf16<128, 0, false, true, false><<<dim3(2, mt128), blk, 0, stream>>>(
        (const void*)h1b, 512, 0, WfcT, 512, 0, bfc, outf, 256, 0, NN, 512, nullptr, nullptr);

    // edge_embeds = relu(ea @ We1 + be1) @ We2 + be2 — fused, 128-row / 8-wave blocks
    edge_mlp<<<MEDGE / 128, dim3(512), 0, stream>>>(ea, We1T, be1, We2T, be2, outf + 5120000);
}